// Round 9
// baseline (1014.634 us; speedup 1.0000x reference)
//
#include <hip/hip_runtime.h>

// Problem constants
#define KC 1024          // num codes
#define DD 256           // embedding dim
#define NP 131072        // B*H*W points
#define HWSZ 4096        // H*W
#define TOTZ 33554432    // B*D*H*W

// d_out float offsets (tuple concat: quantized, loss, indices, cluster_size, ema_emb)
#define OUT_Q    0
#define OUT_LOSS 33554432
#define OUT_IDX  33554433
#define OUT_CS   33685505
#define OUT_EMA  33686529

// workspace float offsets
#define WS_IDX    0         // int[131072]
#define WS_COUNTS 131072    // float[1024]
#define WS_RCNT   132096    // int[1]  (memset together with counts: 1025 floats)
#define WS_LOSSP  132352    // float[256]
#define WS_ENORM  132608    // float[1024]
#define WS_RLIST  133632    // int[131072]
#define WS_EAUG   264704    // ushort[786432] = 393216 floats (8 cc x 12 ks x 16KB)
#define WS_ZAUG   657920    // ushort[67108864] = 33554432 floats (1024 pt x 8 ksA x 16KB)
#define WS_NEED_FLOATS (WS_ZAUG + 33554432)

#define MARGIN 0.0625f
#define RTILE 16

typedef __attribute__((ext_vector_type(8))) short bf16x8;
typedef __attribute__((ext_vector_type(4))) float f32x4;

__device__ inline unsigned short f2bf_rne(float x) {
    unsigned u = __float_as_uint(x);
    unsigned r = u + 0x7FFFu + ((u >> 16) & 1u);
    return (unsigned short)(r >> 16);
}
__device__ inline float bf2f(unsigned short h) {
    return __uint_as_float(((unsigned)h) << 16);
}
__device__ inline void gl_lds16(const void* g, void* l) {
    __builtin_amdgcn_global_load_lds(
        (const __attribute__((address_space(1))) unsigned int*)g,
        (__attribute__((address_space(3))) unsigned int*)l, 16, 0, 0);
}
// monotone float->uint, packed with code index: min key = min dist, tie -> min idx
__device__ inline unsigned long long packkey(float d, int c) {
    unsigned u = __float_as_uint(d);
    u = (u & 0x80000000u) ? ~u : (u | 0x80000000u);
    return (((unsigned long long)u) << 32) | (unsigned)c;
}

__global__ __launch_bounds__(256) void enorm_kernel(const float* __restrict__ emb,
                                                    float* __restrict__ enorm) {
    const int k = blockIdx.x;
    float v = emb[k * DD + threadIdx.x];
    v *= v;
    #pragma unroll
    for (int off = 32; off > 0; off >>= 1) v += __shfl_down(v, off);
    __shared__ float red[4];
    if ((threadIdx.x & 63) == 0) red[threadIdx.x >> 6] = v;
    __syncthreads();
    if (threadIdx.x == 0) enorm[k] = (red[0] + red[1]) + (red[2] + red[3]);
}

// z_aug: [pt(1024)][ksA(8)][kc(2)][mt(8)][lane(64)][8 bf16]
// ksA 0..3 = hi, 4..7 = mid. One block computes hi AND mid (z read once).
// (Proven clean in R0/R1 — restored; the fused-conversion variant spilled.)
__global__ __launch_bounds__(256) void convert_z_kernel(
    const float* __restrict__ z, unsigned short* __restrict__ zaug)
{
    const int blk = blockIdx.x;            // pt*4 + kslot
    const int pt = blk >> 2, kslot = blk & 3;
    const int kbase0 = kslot * 64;
    unsigned short* outH = zaug + (size_t)(pt * 8 + kslot) * 8192;
    unsigned short* outM = zaug + (size_t)(pt * 8 + 4 + kslot) * 8192;
    #pragma unroll
    for (int i = 0; i < 4; ++i) {
        const int f = i * 256 + threadIdx.x;   // fragment index [0,1024)
        const int kc = f >> 9, mt = (f >> 6) & 7, lane = f & 63;
        const int q = lane >> 4, col = lane & 15;
        const int p = pt * 128 + mt * 16 + col;
        const int b = p >> 12, hw = p & 4095;
        const int k0 = kbase0 + kc * 32 + q * 8;
        const float* src = z + (size_t)b * 1048576 + (size_t)k0 * 4096 + hw;
        unsigned short vh[8], vm[8];
        #pragma unroll
        for (int j = 0; j < 8; ++j) {
            const float x = src[j * 4096];
            const unsigned short h = f2bf_rne(x);
            vh[j] = h;
            vm[j] = f2bf_rne(x - bf2f(h));
        }
        *(uint4*)(outH + (size_t)f * 8) = *(uint4*)vh;
        *(uint4*)(outM + (size_t)f * 8) = *(uint4*)vm;
    }
}

// emb_aug: [cc(8)][ks(12)][kc(2)][nt(8)][lane(64)][8 bf16]; ks 0..3 hi, 8..11 mid.
// ks 4..7 are not read -> only 8 ks generated.
__global__ __launch_bounds__(256) void convert_emb_kernel(
    const float* __restrict__ emb, unsigned short* __restrict__ eaug)
{
    const int blk = blockIdx.x;            // cc*8 + ks'
    const int cc = blk >> 3, ksp = blk & 7;
    const int ks = ksp + ((ksp >= 4) ? 4 : 0);   // {0,1,2,3,8,9,10,11}
    const int mode = (ks >= 8);
    unsigned short* outp = eaug + (size_t)(cc * 12 + ks) * 8192;
    #pragma unroll
    for (int i = 0; i < 4; ++i) {
        const int f = i * 256 + threadIdx.x;
        const int kc = f >> 9, nt = (f >> 6) & 7, lane = f & 63;
        const int q = lane >> 4, col = lane & 15;
        const int n = cc * 128 + nt * 16 + col;
        const int k0 = ((ks * 64) & 255) + kc * 32 + q * 8;
        const float* src = emb + (size_t)n * 256 + k0;
        unsigned short v[8];
        #pragma unroll
        for (int j = 0; j < 8; ++j) {
            const float x = src[j];
            const unsigned short h = f2bf_rne(x);
            v[j] = mode ? f2bf_rne(x - bf2f(h)) : h;
        }
        *(uint4*)(outp + (size_t)f * 8) = *(uint4*)v;
    }
}

// MFMA GEMM + fused argmin. R9: 1024 threads = 16 waves, 4 waves/SIMD
// (128-reg cap), A staged via global_load_lds from precomputed zaug
// (staging = pure address calc, ~6 regs, no conversion VALU/registers —
// the fused variant spilled 590-717 MB in R6-R8).
// Phase schedule overlaps mid-slab staging with compute: issue hi -> barrier
// -> issue mid -> phase A (B-mid ks8-11, A-hi only) -> barrier (g=0 only)
// -> phase B (B-hi ks0-3, A-hi + A-mid). Single-buffered B fragments
// (peak 16 regs); 4-wave/SIMD TLP hides B L2 latency.
// Live set: acc 64 (AGPR) + B 16 + af 8 + addr ~12 = ~100 <= 128.
__global__ __launch_bounds__(1024, 4) void gemm_argmin_kernel(
    const unsigned short* __restrict__ zaug, const unsigned short* __restrict__ eaug,
    const float* __restrict__ enorm, int* __restrict__ idx_out,
    float* __restrict__ idx_out_f, float* __restrict__ counts,
    int* __restrict__ rcnt, int* __restrict__ rlist)
{
    __shared__ float smem[38912];                 // 128 KB A slabs + 24 KB dump
    unsigned short* aS = (unsigned short*)smem;   // [slab8][kc2][mt8][lane64][8]
    float* dB = smem + 32768;                     // [16w][16slot][4q][2h]
    float* dS = smem + 32768 + 2048;
    int*   dI = (int*)(smem + 32768 + 4096);
    const int t = threadIdx.x, w = t >> 6, lane = t & 63;
    const int q = lane >> 4, col = lane & 15;
    const int pt = blockIdx.x;                    // 1024 tiles of 128 points

    const unsigned short* zb = zaug + (size_t)pt * 65536;   // halfword units

    // issue hi slabs 0-3 (64 KB) via async global->LDS
    #pragma unroll
    for (int i = 0; i < 4; ++i) {
        const int off = i * 8192 + w * 512 + lane * 8;
        gl_lds16(zb + off, aS + off);
    }
    __syncthreads();                              // hi resident (vmcnt drained)
    // issue mid slabs 4-7 -- land under g=0 phase A
    #pragma unroll
    for (int i = 4; i < 8; ++i) {
        const int off = i * 8192 + w * 512 + lane * 8;
        gl_lds16(zb + off, aS + off);
    }

    // wave w owns codes [w*64, w*64+64); B base (L2-hot)
    const unsigned short* eb = eaug + (size_t)(w >> 1) * 98304
                             + (w & 1) * 2048 + (size_t)lane * 8;

// af in pairs (8 arch regs) -> 16 MFMA per invocation; mi order preserved.
#define COMPUTE_SET(BREG, SLAB)                                               \
    {                                                                         \
        _Pragma("unroll")                                                     \
        for (int mp = 0; mp < 2; ++mp) {                                      \
            bf16x8 af0 = *(const bf16x8*)(aS + (SLAB) * 8192 + kci * 4096     \
                                          + (g4 + mp * 2) * 512 + lane * 8);  \
            bf16x8 af1 = *(const bf16x8*)(aS + (SLAB) * 8192 + kci * 4096     \
                                          + (g4 + mp * 2 + 1) * 512           \
                                          + lane * 8);                        \
            __builtin_amdgcn_s_setprio(1);                                    \
            _Pragma("unroll")                                                 \
            for (int ni = 0; ni < 4; ++ni)                                    \
                acc[mp * 2][ni] = __builtin_amdgcn_mfma_f32_16x16x32_bf16(    \
                    af0, BREG[ni], acc[mp * 2][ni], 0, 0, 0);                 \
            _Pragma("unroll")                                                 \
            for (int ni = 0; ni < 4; ++ni)                                    \
                acc[mp * 2 + 1][ni] = __builtin_amdgcn_mfma_f32_16x16x32_bf16(\
                    af1, BREG[ni], acc[mp * 2 + 1][ni], 0, 0, 0);             \
            __builtin_amdgcn_s_setprio(0);                                    \
        }                                                                     \
    }

    #pragma unroll 1
    for (int g = 0; g < 2; ++g) {
        const int g4 = g * 4;
        f32x4 acc[4][4];
        #pragma unroll
        for (int mi = 0; mi < 4; ++mi)
            #pragma unroll
            for (int ni = 0; ni < 4; ++ni) acc[mi][ni] = (f32x4){0.f, 0.f, 0.f, 0.f};

        // phase A: B mid (ks 8..11), A hi slabs only (mid still in flight @ g=0)
        #pragma unroll 1
        for (int s4 = 0; s4 < 4; ++s4) {
            const int ksE = 8 + s4, slabH = s4;
            bf16x8 bf[4];
            #pragma unroll
            for (int ni = 0; ni < 4; ++ni)
                bf[ni] = *(const bf16x8*)(eb + ksE * 8192 + ni * 512);
            {
                const int kci = 0;
                COMPUTE_SET(bf, slabH)
            }
            #pragma unroll
            for (int ni = 0; ni < 4; ++ni)
                bf[ni] = *(const bf16x8*)(eb + ksE * 8192 + 4096 + ni * 512);
            {
                const int kci = 1;
                COMPUTE_SET(bf, slabH)
            }
        }
        if (g == 0) __syncthreads();              // mid slabs resident
        // phase B: B hi (ks 0..3), A hi + A mid
        #pragma unroll 1
        for (int s4 = 0; s4 < 4; ++s4) {
            const int ksE = s4, slabH = s4;
            bf16x8 bf[4];
            #pragma unroll
            for (int ni = 0; ni < 4; ++ni)
                bf[ni] = *(const bf16x8*)(eb + ksE * 8192 + ni * 512);
            {
                const int kci = 0;
                COMPUTE_SET(bf, slabH)
                COMPUTE_SET(bf, 4 + slabH)
            }
            #pragma unroll
            for (int ni = 0; ni < 4; ++ni)
                bf[ni] = *(const bf16x8*)(eb + ksE * 8192 + 4096 + ni * 512);
            {
                const int kci = 1;
                COMPUTE_SET(bf, slabH)
                COMPUTE_SET(bf, 4 + slabH)
            }
        }

        // per-g epilogue: dist = en - 2*dot; ni-merge, 3-step col shfl-reduce,
        // dump 2 survivors per 16-lane group, final per-point reduce (t<64).
        const int wbase = w * 64;
        #pragma unroll
        for (int mi = 0; mi < 4; ++mi) {
            #pragma unroll
            for (int r = 0; r < 4; ++r) {
                const float en0 = enorm[wbase + col];
                const float en1 = enorm[wbase + 16 + col];
                const float en2 = enorm[wbase + 32 + col];
                const float en3 = enorm[wbase + 48 + col];
                float v0 = fmaf(-2.f, acc[mi][0][r], en0);
                float v1 = fmaf(-2.f, acc[mi][1][r], en1);
                float v2 = fmaf(-2.f, acc[mi][2][r], en2);
                float v3 = fmaf(-2.f, acc[mi][3][r], en3);
                const int nb = wbase + col;
                float b01 = fminf(v0, v1), x01 = fmaxf(v0, v1);
                int   i01 = (v1 < v0) ? nb + 16 : nb;
                float b23 = fminf(v2, v3), x23 = fmaxf(v2, v3);
                int   i23 = (v3 < v2) ? nb + 48 : nb + 32;
                float b = fminf(b01, b23);
                int   ib = (b23 < b01) ? i23 : i01;
                float s2 = fminf(fmaxf(b01, b23), fminf(x01, x23));
                #pragma unroll
                for (int m = 1; m < 8; m <<= 1) {             // cols 16 -> 2
                    const float ob = __shfl_xor(b, m);
                    const float os = __shfl_xor(s2, m);
                    const int   oi = __shfl_xor(ib, m);
                    const bool sw = ob < b;
                    const float cand = sw ? b : ob;           // loser's best
                    const float osel = sw ? os : s2;          // winner's 2nd
                    b  = sw ? ob : b;
                    ib = sw ? oi : ib;
                    s2 = fminf(cand, osel);
                }
                if ((col & 7) == 0) {
                    const int slot = mi * 4 + r;
                    const int di = w * 128 + slot * 8 + q * 2 + (col >> 3);
                    dB[di] = b; dS[di] = s2; dI[di] = ib;
                }
            }
        }
        __syncthreads();                          // dumps visible
        if (t < 64) {
            const int mi = t >> 4, qq = (t >> 2) & 3, rr = t & 3;
            const int slot = mi * 4 + rr;
            float B = 3.4e38f, S = 3.4e38f; int I = 0;
            #pragma unroll
            for (int wv = 0; wv < 16; ++wv) {
                #pragma unroll
                for (int h = 0; h < 2; ++h) {
                    const int di = wv * 128 + slot * 8 + qq * 2 + h;
                    const float b = dB[di];
                    const float s2 = dS[di];
                    const int   i = dI[di];
                    if (b < B) { S = fminf(B, s2); B = b; I = i; }
                    else       { S = fminf(S, b); }
                }
            }
            const int p = pt * 128 + g * 64 + t;  // t == mi*16+qq*4+rr
            idx_out[p] = I;
            idx_out_f[p] = (float)I;
            atomicAdd(&counts[I], 1.0f);
            if (S - B < MARGIN) {
                const int pos = atomicAdd(rcnt, 1);
                rlist[pos] = p;
            }
        }
        __syncthreads();                          // dump region reusable
    }
#undef COMPUTE_SET
}

// Batched exact fp32 re-argmin: 16 points staged in LDS, each thread owns 4
// codes (c = ci*256 + t) with dot[16][4] register accumulators -> per d4 only
// 16 LDS reads + 4 e-loads for 256 FMA. Numerics identical to prior version.
__global__ __launch_bounds__(256) void rescue_kernel(
    const float* __restrict__ z, const float* __restrict__ emb,
    const float* __restrict__ enorm, const int* __restrict__ rcnt,
    const int* __restrict__ rlist, int* __restrict__ idx_out,
    float* __restrict__ idx_out_f, float* __restrict__ counts)
{
    __shared__ float zl[RTILE][DD];
    __shared__ unsigned long long lkey[RTILE];
    const int n = *rcnt;
    if (n <= 0) return;
    const int ntiles = (n + RTILE - 1) / RTILE;
    const int t = threadIdx.x;
    const int slot = t & 15, drow = t >> 4;    // thread loads 16 dims for one slot
    #pragma unroll 1
    for (int tile = blockIdx.x; tile < ntiles; tile += gridDim.x) {
        const int base = tile * RTILE;
        {
            const int ridx = min(base + slot, n - 1);   // clamp: dup compute, guarded update
            const int p = rlist[ridx];
            const int b = p >> 12, hw = p & 4095;
            const float* zp = z + (size_t)b * 1048576 + hw;
            #pragma unroll
            for (int j = 0; j < 16; ++j)
                zl[slot][drow * 16 + j] = zp[(size_t)(drow * 16 + j) * 4096];
        }
        if (t < RTILE) lkey[t] = ~0ull;
        __syncthreads();
        float dot[RTILE][4];
        #pragma unroll
        for (int p = 0; p < RTILE; ++p)
            #pragma unroll
            for (int ci = 0; ci < 4; ++ci) dot[p][ci] = 0.f;
        #pragma unroll 1
        for (int d4 = 0; d4 < 64; ++d4) {
            float4 ev[4];
            #pragma unroll
            for (int ci = 0; ci < 4; ++ci)
                ev[ci] = *(const float4*)(emb + (size_t)(ci * 256 + t) * 256 + d4 * 4);
            #pragma unroll
            for (int p = 0; p < RTILE; ++p) {
                const float4 zv = *(const float4*)(&zl[p][d4 * 4]);
                #pragma unroll
                for (int ci = 0; ci < 4; ++ci) {
                    dot[p][ci] = fmaf(zv.x, ev[ci].x, dot[p][ci]);
                    dot[p][ci] = fmaf(zv.y, ev[ci].y, dot[p][ci]);
                    dot[p][ci] = fmaf(zv.z, ev[ci].z, dot[p][ci]);
                    dot[p][ci] = fmaf(zv.w, ev[ci].w, dot[p][ci]);
                }
            }
        }
        float en[4];
        #pragma unroll
        for (int ci = 0; ci < 4; ++ci) en[ci] = enorm[ci * 256 + t];
        #pragma unroll
        for (int p = 0; p < RTILE; ++p) {
            unsigned long long k = packkey(fmaf(-2.f, dot[p][0], en[0]), t);
            #pragma unroll
            for (int ci = 1; ci < 4; ++ci) {
                const unsigned long long k2 =
                    packkey(fmaf(-2.f, dot[p][ci], en[ci]), ci * 256 + t);
                k = (k2 < k) ? k2 : k;
            }
            atomicMin(&lkey[p], k);
        }
        __syncthreads();
        if (t < RTILE && base + t < n) {
            const int p = rlist[base + t];
            const int fc = (int)(lkey[t] & 0xFFFFFFFFull);
            const int old = idx_out[p];
            if (fc != old) {
                atomicAdd(&counts[old], -1.0f);
                atomicAdd(&counts[fc], 1.0f);
                idx_out[p] = fc;
                idx_out_f[p] = (float)fc;
            }
        }
        __syncthreads();
    }
}

// Fused quantize + dw-segment-sum + loss. Block = one dim d (256 blocks x 512 thr).
// kdw parity-split (t&1) to halve LDS-atomic same-address serialization.
__global__ __launch_bounds__(512) void dwq_kernel(
    const float* __restrict__ z, const float* __restrict__ emb,
    const int* __restrict__ idx, const float* __restrict__ ema_emb,
    float* __restrict__ out_q, float* __restrict__ out_ema,
    float* __restrict__ lossp)
{
    __shared__ float kdw[2][KC];
    __shared__ float ecol[KC];
    __shared__ float red[8];
    const int d = blockIdx.x;
    const int t = threadIdx.x;
    #pragma unroll
    for (int k = t; k < KC; k += 512) {
        kdw[0][k] = 0.f; kdw[1][k] = 0.f;
        ecol[k] = emb[(size_t)k * 256 + d];
    }
    __syncthreads();
    float* kd = kdw[t & 1];
    float ls = 0.f;
    #pragma unroll 1
    for (int it = 0; it < 64; ++it) {
        const int e = it * 512 + t;            // float4-unit over (b, hw)
        const int b = e >> 10, hwi = (e & 1023) << 2;
        const size_t zoff = (size_t)b * 1048576 + (size_t)d * 4096 + hwi;
        const float4 zv = *(const float4*)(z + zoff);
        const int4 iv = *(const int4*)(idx + b * 4096 + hwi);
        const float q0 = ecol[iv.x], q1 = ecol[iv.y], q2 = ecol[iv.z], q3 = ecol[iv.w];
        float4 qv; qv.x = q0; qv.y = q1; qv.z = q2; qv.w = q3;
        *(float4*)(out_q + zoff) = qv;
        atomicAdd(&kd[iv.x], zv.x);
        atomicAdd(&kd[iv.y], zv.y);
        atomicAdd(&kd[iv.z], zv.z);
        atomicAdd(&kd[iv.w], zv.w);
        const float d0 = zv.x - q0, d1 = zv.y - q1, d2 = zv.z - q2, d3 = zv.w - q3;
        ls += (d0 * d0 + d1 * d1) + (d2 * d2 + d3 * d3);
    }
    __syncthreads();
    #pragma unroll
    for (int k = t; k < KC; k += 512)
        out_ema[(size_t)k * 256 + d] = 0.99f * ema_emb[(size_t)k * 256 + d]
                                     + 0.01f * (kdw[0][k] + kdw[1][k]);
    #pragma unroll
    for (int off = 32; off > 0; off >>= 1) ls += __shfl_down(ls, off);
    if ((t & 63) == 0) red[t >> 6] = ls;
    __syncthreads();
    if (t == 0) {
        float s = 0.f;
        #pragma unroll
        for (int i = 0; i < 8; ++i) s += red[i];
        lossp[blockIdx.x] = s;
    }
}

__global__ __launch_bounds__(256) void finalize_kernel(
    const float* __restrict__ ema_cs, const float* __restrict__ counts,
    const float* __restrict__ lossp, float* __restrict__ out)
{
    const int i = blockIdx.x * 256 + threadIdx.x;   // 4 blocks
    out[OUT_CS + i] = 0.99f * ema_cs[i] + 0.01f * counts[i];
    if (blockIdx.x == 0) {
        float s = lossp[threadIdx.x];
        #pragma unroll
        for (int off = 32; off > 0; off >>= 1) s += __shfl_down(s, off);
        __shared__ float red[4];
        if ((threadIdx.x & 63) == 0) red[threadIdx.x >> 6] = s;
        __syncthreads();
        if (threadIdx.x == 0)
            out[OUT_LOSS] = 0.25f * ((red[0] + red[1]) + (red[2] + red[3])) / 33554432.0f;
    }
}

// ---------- fallback fp32 GEMM (used if ws too small) ----------
__global__ __launch_bounds__(256) void dist_argmin_kernel(
    const float* __restrict__ z, const float* __restrict__ emb,
    const float* __restrict__ enorm, int* __restrict__ idx_out,
    float* __restrict__ idx_out_f, float* __restrict__ counts)
{
    __shared__ float smem[4096];
    float* As = smem;
    float* Bs = smem + 1024;
    const int tid = threadIdx.x;
    const int tx = tid & 15, ty = tid >> 4;
    const int p0 = blockIdx.x * 128;
    const int b = p0 >> 12, hw0 = p0 & 4095;
    const float* zb = z + (size_t)b * (DD * HWSZ) + hw0;
    const int arow = (tid & 31) * 4, akd = tid >> 5;
    const int bcode = tid >> 1, bj = (tid & 1) * 4;
    float best[8]; int bidx[8];
    #pragma unroll
    for (int i = 0; i < 8; i++) { best[i] = 3.4e38f; bidx[i] = 0; }
    #pragma unroll 1
    for (int cc = 0; cc < 8; ++cc) {
        const int c0 = cc * 128;
        float acc[8][8];
        #pragma unroll
        for (int i = 0; i < 8; i++)
            #pragma unroll
            for (int j = 0; j < 8; j++) acc[i][j] = 0.0f;
        #pragma unroll 1
        for (int dk = 0; dk < 32; ++dk) {
            const int kk0 = dk * 8;
            const float4 av = *(const float4*)(zb + (kk0 + akd) * HWSZ + arow);
            const float4 bv = *(const float4*)(emb + (c0 + bcode) * DD + kk0 + bj);
            __syncthreads();
            *(float4*)(As + akd * 128 + arow) = av;
            Bs[(bj + 0) * 128 + bcode] = bv.x;
            Bs[(bj + 1) * 128 + bcode] = bv.y;
            Bs[(bj + 2) * 128 + bcode] = bv.z;
            Bs[(bj + 3) * 128 + bcode] = bv.w;
            __syncthreads();
            #pragma unroll
            for (int kk = 0; kk < 8; ++kk) {
                const float4 a0 = *(const float4*)(As + kk * 128 + ty * 8);
                const float4 a1 = *(const float4*)(As + kk * 128 + ty * 8 + 4);
                const float4 b0 = *(const float4*)(Bs + kk * 128 + tx * 8);
                const float4 b1 = *(const float4*)(Bs + kk * 128 + tx * 8 + 4);
                const float a[8] = {a0.x,a0.y,a0.z,a0.w,a1.x,a1.y,a1.z,a1.w};
                const float bb[8] = {b0.x,b0.y,b0.z,b0.w,b1.x,b1.y,b1.z,b1.w};
                #pragma unroll
                for (int i = 0; i < 8; i++)
                    #pragma unroll
                    for (int j = 0; j < 8; j++)
                        acc[i][j] = fmaf(a[i], bb[j], acc[i][j]);
            }
        }
        const float4 en0 = *(const float4*)(enorm + c0 + tx * 8);
        const float4 en1 = *(const float4*)(enorm + c0 + tx * 8 + 4);
        const float en[8] = {en0.x,en0.y,en0.z,en0.w,en1.x,en1.y,en1.z,en1.w};
        #pragma unroll
        for (int j = 0; j < 8; j++) {
            const int c = c0 + tx * 8 + j;
            #pragma unroll
            for (int i = 0; i < 8; i++) {
                const float dist = fmaf(-2.0f, acc[i][j], en[j]);
                if (dist < best[i]) { best[i] = dist; bidx[i] = c; }
            }
        }
    }
    __syncthreads();
    float* rmin = smem;
    int* ridx = (int*)(smem + 2048);
    #pragma unroll
    for (int i = 0; i < 8; i++) {
        const int r = ty * 8 + i;
        rmin[r * 16 + tx] = best[i];
        ridx[r * 16 + tx] = bidx[i];
    }
    __syncthreads();
    if (tid < 128) {
        const int r = tid;
        float m = rmin[r * 16]; int mi = ridx[r * 16];
        #pragma unroll
        for (int tt = 1; tt < 16; tt++) {
            const float v = rmin[r * 16 + tt];
            const int vi = ridx[r * 16 + tt];
            if (v < m || (v == m && vi < mi)) { m = v; mi = vi; }
        }
        const int p = p0 + r;
        idx_out[p] = mi;
        idx_out_f[p] = (float)mi;
        atomicAdd(&counts[mi], 1.0f);
    }
}

extern "C" void kernel_launch(void* const* d_in, const int* in_sizes, int n_in,
                              void* d_out, int out_size, void* d_ws, size_t ws_size,
                              hipStream_t stream) {
    const float* z       = (const float*)d_in[0];
    const float* emb     = (const float*)d_in[1];
    const float* ema_cs  = (const float*)d_in[2];
    const float* ema_emb = (const float*)d_in[3];
    float* out = (float*)d_out;
    float* ws  = (float*)d_ws;

    int*   ws_idx    = (int*)(ws + WS_IDX);
    float* ws_counts = ws + WS_COUNTS;
    int*   ws_rcnt   = (int*)(ws + WS_RCNT);
    float* ws_lossp  = ws + WS_LOSSP;
    float* ws_enorm  = ws + WS_ENORM;
    int*   ws_rlist  = (int*)(ws + WS_RLIST);
    unsigned short* ws_eaug = (unsigned short*)(ws + WS_EAUG);
    unsigned short* ws_zaug = (unsigned short*)(ws + WS_ZAUG);

    // zero counts + rescue counter
    hipMemsetAsync(ws_counts, 0, 1025 * sizeof(float), stream);
    hipLaunchKernelGGL(enorm_kernel, dim3(KC), dim3(256), 0, stream, emb, ws_enorm);

    if (ws_size >= (size_t)WS_NEED_FLOATS * sizeof(float)) {
        hipLaunchKernelGGL(convert_z_kernel, dim3(4096), dim3(256), 0, stream, z, ws_zaug);
        hipLaunchKernelGGL(convert_emb_kernel, dim3(64), dim3(256), 0, stream, emb, ws_eaug);
        hipLaunchKernelGGL(gemm_argmin_kernel, dim3(1024), dim3(1024), 0, stream,
                           ws_zaug, ws_eaug, ws_enorm, ws_idx, out + OUT_IDX,
                           ws_counts, ws_rcnt, ws_rlist);
        hipLaunchKernelGGL(rescue_kernel, dim3(512), dim3(256), 0, stream,
                           z, emb, ws_enorm, ws_rcnt, ws_rlist,
                           ws_idx, out + OUT_IDX, ws_counts);
    } else {
        hipLaunchKernelGGL(dist_argmin_kernel, dim3(NP / 128), dim3(256), 0, stream,
                           z, emb, ws_enorm, ws_idx, out + OUT_IDX, ws_counts);
    }

    hipLaunchKernelGGL(dwq_kernel, dim3(DD), dim3(512), 0, stream,
                       z, emb, ws_idx, ema_emb, out, out + OUT_EMA, ws_lossp);
    hipLaunchKernelGGL(finalize_kernel, dim3(4), dim3(256), 0, stream,
                       ema_cs, ws_counts, ws_lossp, out);
}

// Round 12
// 782.234 us; speedup vs baseline: 1.2971x; 1.2971x over previous
//
#include <hip/hip_runtime.h>

// Problem constants
#define KC 1024          // num codes
#define DD 256           // embedding dim
#define NP 131072        // B*H*W points
#define HWSZ 4096        // H*W
#define TOTZ 33554432    // B*D*H*W

// d_out float offsets (tuple concat: quantized, loss, indices, cluster_size, ema_emb)
#define OUT_Q    0
#define OUT_LOSS 33554432
#define OUT_IDX  33554433
#define OUT_CS   33685505
#define OUT_EMA  33686529

// workspace float offsets
#define WS_IDX    0         // int[131072]
#define WS_COUNTS 131072    // float[1024]
#define WS_RCNT   132096    // int[1]  (memset together with counts: 1025 floats)
#define WS_LOSSP  132352    // float[256]
#define WS_ENORM  132608    // float[1024]
#define WS_RLIST  133632    // int[131072]
#define WS_EAUG   264704    // ushort[786432] = 393216 floats (8 cc x 12 ks x 16KB)
#define WS_ZAUG   657920    // ushort[67108864] = 33554432 floats (1024 pt x 8 ksA x 16KB)
#define WS_NEED_FLOATS (WS_ZAUG + 33554432)

#define MARGIN 0.0625f
#define RTILE 16

typedef __attribute__((ext_vector_type(8))) short bf16x8;
typedef __attribute__((ext_vector_type(4))) float f32x4;

__device__ inline unsigned short f2bf_rne(float x) {
    unsigned u = __float_as_uint(x);
    unsigned r = u + 0x7FFFu + ((u >> 16) & 1u);
    return (unsigned short)(r >> 16);
}
__device__ inline float bf2f(unsigned short h) {
    return __uint_as_float(((unsigned)h) << 16);
}
__device__ inline void gl_lds16(const void* g, void* l) {
    __builtin_amdgcn_global_load_lds(
        (const __attribute__((address_space(1))) unsigned int*)g,
        (__attribute__((address_space(3))) unsigned int*)l, 16, 0, 0);
}
// monotone float->uint, packed with code index: min key = min dist, tie -> min idx
__device__ inline unsigned long long packkey(float d, int c) {
    unsigned u = __float_as_uint(d);
    u = (u & 0x80000000u) ? ~u : (u | 0x80000000u);
    return (((unsigned long long)u) << 32) | (unsigned)c;
}

__global__ __launch_bounds__(256) void enorm_kernel(const float* __restrict__ emb,
                                                    float* __restrict__ enorm) {
    const int k = blockIdx.x;
    float v = emb[k * DD + threadIdx.x];
    v *= v;
    #pragma unroll
    for (int off = 32; off > 0; off >>= 1) v += __shfl_down(v, off);
    __shared__ float red[4];
    if ((threadIdx.x & 63) == 0) red[threadIdx.x >> 6] = v;
    __syncthreads();
    if (threadIdx.x == 0) enorm[k] = (red[0] + red[1]) + (red[2] + red[3]);
}

// z_aug: [pt(1024)][ksA(8)][kc(2)][mt(8)][lane(64)][8 bf16]
// ksA 0..3 = hi, 4..7 = mid. One block computes hi AND mid (z read once).
__global__ __launch_bounds__(256) void convert_z_kernel(
    const float* __restrict__ z, unsigned short* __restrict__ zaug)
{
    const int blk = blockIdx.x;            // pt*4 + kslot
    const int pt = blk >> 2, kslot = blk & 3;
    const int kbase0 = kslot * 64;
    unsigned short* outH = zaug + (size_t)(pt * 8 + kslot) * 8192;
    unsigned short* outM = zaug + (size_t)(pt * 8 + 4 + kslot) * 8192;
    #pragma unroll
    for (int i = 0; i < 4; ++i) {
        const int f = i * 256 + threadIdx.x;   // fragment index [0,1024)
        const int kc = f >> 9, mt = (f >> 6) & 7, lane = f & 63;
        const int q = lane >> 4, col = lane & 15;
        const int p = pt * 128 + mt * 16 + col;
        const int b = p >> 12, hw = p & 4095;
        const int k0 = kbase0 + kc * 32 + q * 8;
        const float* src = z + (size_t)b * 1048576 + (size_t)k0 * 4096 + hw;
        unsigned short vh[8], vm[8];
        #pragma unroll
        for (int j = 0; j < 8; ++j) {
            const float x = src[j * 4096];
            const unsigned short h = f2bf_rne(x);
            vh[j] = h;
            vm[j] = f2bf_rne(x - bf2f(h));
        }
        *(uint4*)(outH + (size_t)f * 8) = *(uint4*)vh;
        *(uint4*)(outM + (size_t)f * 8) = *(uint4*)vm;
    }
}

// emb_aug: [cc(8)][ks(12)][kc(2)][nt(8)][lane(64)][8 bf16]; ks 0..3 hi, 8..11 mid.
// ks 4..7 are not read -> only 8 ks generated.
__global__ __launch_bounds__(256) void convert_emb_kernel(
    const float* __restrict__ emb, unsigned short* __restrict__ eaug)
{
    const int blk = blockIdx.x;            // cc*8 + ks'
    const int cc = blk >> 3, ksp = blk & 7;
    const int ks = ksp + ((ksp >= 4) ? 4 : 0);   // {0,1,2,3,8,9,10,11}
    const int mode = (ks >= 8);
    unsigned short* outp = eaug + (size_t)(cc * 12 + ks) * 8192;
    #pragma unroll
    for (int i = 0; i < 4; ++i) {
        const int f = i * 256 + threadIdx.x;
        const int kc = f >> 9, nt = (f >> 6) & 7, lane = f & 63;
        const int q = lane >> 4, col = lane & 15;
        const int n = cc * 128 + nt * 16 + col;
        const int k0 = ((ks * 64) & 255) + kc * 32 + q * 8;
        const float* src = emb + (size_t)n * 256 + k0;
        unsigned short v[8];
        #pragma unroll
        for (int j = 0; j < 8; ++j) {
            const float x = src[j];
            const unsigned short h = f2bf_rne(x);
            v[j] = mode ? f2bf_rne(x - bf2f(h)) : h;
        }
        *(uint4*)(outp + (size_t)f * 8) = *(uint4*)v;
    }
}

// MFMA GEMM + fused argmin. R10/R11: 768 threads = 12 waves -> 3 waves/SIMD
// with a 170-reg cap (the 4/SIMD 128-reg budget spilled in R6/R7/R9; R1
// measured 168 total regs clean -> 170 is the feasible occupancy step).
// Work: 32 wave-tiles (pt-half x 16 code-groups of 64); wave w takes tiles
// {w, w+12, w+24} (waves 8-11 get 2). A (hi+mid, 128 KB) staged once via
// global_load_lds; tile #1 runs phase A (B-mid ks8-11 x A-hi) while mid slabs
// are in flight, ONE barrier, then all remaining work barrier-free.
// Per-tile epilogue: full 16->1 col shfl-reduce, (best,2nd,idx) per point per
// code-group into 24 KB LDS dump; final t<128 pass merges 16 groups.
// Live set: acc 64 + bf 16 + af 8 + addr/temps ~30 = ~120 <= 170.
// MFMA accumulation order per acc identical to R9 -> absmax 0.03125.
__global__ __launch_bounds__(768, 3) void gemm_argmin_kernel(
    const unsigned short* __restrict__ zaug, const unsigned short* __restrict__ eaug,
    const float* __restrict__ enorm, int* __restrict__ idx_out,
    float* __restrict__ idx_out_f, float* __restrict__ counts,
    int* __restrict__ rcnt, int* __restrict__ rlist)
{
    __shared__ float smem[38912];                 // 128 KB A slabs + 24 KB dump
    unsigned short* aS = (unsigned short*)smem;   // [slab8][kc2][mt8][lane64][8]
    float* dB = smem + 32768;                     // [16cg][128pt]
    float* dS = smem + 34816;
    int*   dI = (int*)(smem + 36864);
    const int t = threadIdx.x, w = t >> 6, lane = t & 63;
    const int q = lane >> 4, col = lane & 15;
    const int pt = blockIdx.x;                    // 1024 tiles of 128 points

    const unsigned short* zb = zaug + (size_t)pt * 65536;   // halfword units

    // issue hi slabs (chunks 0..4095, 16B each); boundary aligns with waves
    #pragma unroll 1
    for (int c = t; c < 4096; c += 768)
        gl_lds16(zb + c * 8, aS + c * 8);
    __syncthreads();                              // hi resident (vmcnt drained)
    // issue mid slabs (chunks 4096..8191) -- land under tile #1 phase A
    #pragma unroll 1
    for (int c = 4096 + t; c < 8192; c += 768)
        gl_lds16(zb + c * 8, aS + c * 8);

// af in pairs (8 arch regs); mi order 0,1,2,3 preserved.
#define COMPUTE_SET(BREG, SLAB)                                               \
    {                                                                         \
        _Pragma("unroll")                                                     \
        for (int mp = 0; mp < 2; ++mp) {                                      \
            bf16x8 af0 = *(const bf16x8*)(aS + (SLAB) * 8192 + kci * 4096     \
                                          + (g4 + mp * 2) * 512 + lane * 8);  \
            bf16x8 af1 = *(const bf16x8*)(aS + (SLAB) * 8192 + kci * 4096     \
                                          + (g4 + mp * 2 + 1) * 512           \
                                          + lane * 8);                        \
            __builtin_amdgcn_s_setprio(1);                                    \
            _Pragma("unroll")                                                 \
            for (int ni = 0; ni < 4; ++ni)                                    \
                acc[mp * 2][ni] = __builtin_amdgcn_mfma_f32_16x16x32_bf16(    \
                    af0, BREG[ni], acc[mp * 2][ni], 0, 0, 0);                 \
            _Pragma("unroll")                                                 \
            for (int ni = 0; ni < 4; ++ni)                                    \
                acc[mp * 2 + 1][ni] = __builtin_amdgcn_mfma_f32_16x16x32_bf16(\
                    af1, BREG[ni], acc[mp * 2 + 1][ni], 0, 0, 0);             \
            __builtin_amdgcn_s_setprio(0);                                    \
        }                                                                     \
    }

// phase A: B mid (ks 8..11) x A hi slabs
#define PHASE_A                                                               \
    _Pragma("unroll 1")                                                       \
    for (int s4 = 0; s4 < 4; ++s4) {                                          \
        const int ksE = 8 + s4, slabH = s4;                                   \
        bf16x8 bf[4];                                                         \
        _Pragma("unroll")                                                     \
        for (int ni = 0; ni < 4; ++ni)                                        \
            bf[ni] = *(const bf16x8*)(eb + ksE * 8192 + ni * 512);            \
        { const int kci = 0; COMPUTE_SET(bf, slabH) }                         \
        _Pragma("unroll")                                                     \
        for (int ni = 0; ni < 4; ++ni)                                        \
            bf[ni] = *(const bf16x8*)(eb + ksE * 8192 + 4096 + ni * 512);     \
        { const int kci = 1; COMPUTE_SET(bf, slabH) }                         \
    }

// phase B: B hi (ks 0..3) x (A hi + A mid)
#define PHASE_B                                                               \
    _Pragma("unroll 1")                                                       \
    for (int s4 = 0; s4 < 4; ++s4) {                                          \
        const int ksE = s4, slabH = s4;                                       \
        bf16x8 bf[4];                                                         \
        _Pragma("unroll")                                                     \
        for (int ni = 0; ni < 4; ++ni)                                        \
            bf[ni] = *(const bf16x8*)(eb + ksE * 8192 + ni * 512);            \
        { const int kci = 0; COMPUTE_SET(bf, slabH) COMPUTE_SET(bf, 4 + slabH) } \
        _Pragma("unroll")                                                     \
        for (int ni = 0; ni < 4; ++ni)                                        \
            bf[ni] = *(const bf16x8*)(eb + ksE * 8192 + 4096 + ni * 512);     \
        { const int kci = 1; COMPUTE_SET(bf, slabH) COMPUTE_SET(bf, 4 + slabH) } \
    }

// epilogue: dist = en - 2*dot; ni-merge; 4-step col shfl-reduce 16->1;
// col==0 lanes write (best,2nd,idx) per point into dump[cg][ptl].
#define EPILOGUE                                                              \
    {                                                                         \
        const int cbase = cg * 64;                                            \
        _Pragma("unroll")                                                     \
        for (int mi = 0; mi < 4; ++mi) {                                      \
            _Pragma("unroll")                                                 \
            for (int r = 0; r < 4; ++r) {                                     \
                const float en0 = enorm[cbase + col];                         \
                const float en1 = enorm[cbase + 16 + col];                    \
                const float en2 = enorm[cbase + 32 + col];                    \
                const float en3 = enorm[cbase + 48 + col];                    \
                float v0 = fmaf(-2.f, acc[mi][0][r], en0);                    \
                float v1 = fmaf(-2.f, acc[mi][1][r], en1);                    \
                float v2 = fmaf(-2.f, acc[mi][2][r], en2);                    \
                float v3 = fmaf(-2.f, acc[mi][3][r], en3);                    \
                const int nb = cbase + col;                                   \
                float b01 = fminf(v0, v1), x01 = fmaxf(v0, v1);               \
                int   i01 = (v1 < v0) ? nb + 16 : nb;                         \
                float b23 = fminf(v2, v3), x23 = fmaxf(v2, v3);               \
                int   i23 = (v3 < v2) ? nb + 48 : nb + 32;                    \
                float b = fminf(b01, b23);                                    \
                int   ib = (b23 < b01) ? i23 : i01;                           \
                float s2 = fminf(fmaxf(b01, b23), fminf(x01, x23));           \
                _Pragma("unroll")                                             \
                for (int m = 1; m < 16; m <<= 1) {                            \
                    const float ob = __shfl_xor(b, m);                        \
                    const float os = __shfl_xor(s2, m);                       \
                    const int   oi = __shfl_xor(ib, m);                       \
                    const bool sw = ob < b;                                   \
                    const float cand = sw ? b : ob;                           \
                    const float osel = sw ? os : s2;                          \
                    b  = sw ? ob : b;                                         \
                    ib = sw ? oi : ib;                                        \
                    s2 = fminf(cand, osel);                                   \
                }                                                             \
                if (col == 0) {                                               \
                    const int ptl = pth * 64 + mi * 16 + q * 4 + r;           \
                    dB[cg * 128 + ptl] = b;                                   \
                    dS[cg * 128 + ptl] = s2;                                  \
                    dI[cg * 128 + ptl] = ib;                                  \
                }                                                             \
            }                                                                 \
        }                                                                     \
    }

#define INIT_ACC                                                              \
    _Pragma("unroll")                                                         \
    for (int mi = 0; mi < 4; ++mi)                                            \
        _Pragma("unroll")                                                     \
        for (int ni = 0; ni < 4; ++ni) acc[mi][ni] = (f32x4){0.f,0.f,0.f,0.f};

#define TILE_SETUP(TAU)                                                       \
    const int pth = (TAU) & 1, cg = (TAU) >> 1;                               \
    const int g4 = pth * 4;                                                   \
    const unsigned short* eb = eaug + (size_t)(cg >> 1) * 98304               \
                             + (cg & 1) * 2048 + (size_t)lane * 8;

    f32x4 acc[4][4];
    {   // tile #1 (tau = w): phase A under mid staging, barrier, phase B
        TILE_SETUP(w)
        INIT_ACC
        PHASE_A
        __syncthreads();                          // mid slabs resident
        PHASE_B
        EPILOGUE
    }
    #pragma unroll 1
    for (int ti = 1; ti < 3; ++ti) {
        const int tau = w + ti * 12;
        if (tau < 32) {
            TILE_SETUP(tau)
            INIT_ACC
            PHASE_A
            PHASE_B
            EPILOGUE
        }
    }
#undef TILE_SETUP
#undef INIT_ACC
#undef EPILOGUE
#undef PHASE_B
#undef PHASE_A
#undef COMPUTE_SET

    __syncthreads();                              // all dumps visible
    if (t < 128) {
        float B = 3.4e38f, S = 3.4e38f; int I = 0;
        #pragma unroll
        for (int cg = 0; cg < 16; ++cg) {
            const float b = dB[cg * 128 + t];
            const float s2 = dS[cg * 128 + t];
            const int   i = dI[cg * 128 + t];
            if (b < B) { S = fminf(B, s2); B = b; I = i; }
            else       { S = fminf(S, b); }
        }
        const int p = pt * 128 + t;
        idx_out[p] = I;
        idx_out_f[p] = (float)I;
        atomicAdd(&counts[I], 1.0f);
        if (S - B < MARGIN) {
            const int pos = atomicAdd(rcnt, 1);
            rlist[pos] = p;
        }
    }
}

// Batched exact fp32 re-argmin: 16 points staged in LDS, each thread owns 4
// codes (c = ci*256 + t) with dot[16][4] register accumulators -> per d4 only
// 16 LDS reads + 4 e-loads for 256 FMA. Numerics identical to prior version.
__global__ __launch_bounds__(256) void rescue_kernel(
    const float* __restrict__ z, const float* __restrict__ emb,
    const float* __restrict__ enorm, const int* __restrict__ rcnt,
    const int* __restrict__ rlist, int* __restrict__ idx_out,
    float* __restrict__ idx_out_f, float* __restrict__ counts)
{
    __shared__ float zl[RTILE][DD];
    __shared__ unsigned long long lkey[RTILE];
    const int n = *rcnt;
    if (n <= 0) return;
    const int ntiles = (n + RTILE - 1) / RTILE;
    const int t = threadIdx.x;
    const int slot = t & 15, drow = t >> 4;    // thread loads 16 dims for one slot
    #pragma unroll 1
    for (int tile = blockIdx.x; tile < ntiles; tile += gridDim.x) {
        const int base = tile * RTILE;
        {
            const int ridx = min(base + slot, n - 1);   // clamp: dup compute, guarded update
            const int p = rlist[ridx];
            const int b = p >> 12, hw = p & 4095;
            const float* zp = z + (size_t)b * 1048576 + hw;
            #pragma unroll
            for (int j = 0; j < 16; ++j)
                zl[slot][drow * 16 + j] = zp[(size_t)(drow * 16 + j) * 4096];
        }
        if (t < RTILE) lkey[t] = ~0ull;
        __syncthreads();
        float dot[RTILE][4];
        #pragma unroll
        for (int p = 0; p < RTILE; ++p)
            #pragma unroll
            for (int ci = 0; ci < 4; ++ci) dot[p][ci] = 0.f;
        #pragma unroll 1
        for (int d4 = 0; d4 < 64; ++d4) {
            float4 ev[4];
            #pragma unroll
            for (int ci = 0; ci < 4; ++ci)
                ev[ci] = *(const float4*)(emb + (size_t)(ci * 256 + t) * 256 + d4 * 4);
            #pragma unroll
            for (int p = 0; p < RTILE; ++p) {
                const float4 zv = *(const float4*)(&zl[p][d4 * 4]);
                #pragma unroll
                for (int ci = 0; ci < 4; ++ci) {
                    dot[p][ci] = fmaf(zv.x, ev[ci].x, dot[p][ci]);
                    dot[p][ci] = fmaf(zv.y, ev[ci].y, dot[p][ci]);
                    dot[p][ci] = fmaf(zv.z, ev[ci].z, dot[p][ci]);
                    dot[p][ci] = fmaf(zv.w, ev[ci].w, dot[p][ci]);
                }
            }
        }
        float en[4];
        #pragma unroll
        for (int ci = 0; ci < 4; ++ci) en[ci] = enorm[ci * 256 + t];
        #pragma unroll
        for (int p = 0; p < RTILE; ++p) {
            unsigned long long k = packkey(fmaf(-2.f, dot[p][0], en[0]), t);
            #pragma unroll
            for (int ci = 1; ci < 4; ++ci) {
                const unsigned long long k2 =
                    packkey(fmaf(-2.f, dot[p][ci], en[ci]), ci * 256 + t);
                k = (k2 < k) ? k2 : k;
            }
            atomicMin(&lkey[p], k);
        }
        __syncthreads();
        if (t < RTILE && base + t < n) {
            const int p = rlist[base + t];
            const int fc = (int)(lkey[t] & 0xFFFFFFFFull);
            const int old = idx_out[p];
            if (fc != old) {
                atomicAdd(&counts[old], -1.0f);
                atomicAdd(&counts[fc], 1.0f);
                idx_out[p] = fc;
                idx_out_f[p] = (float)fc;
            }
        }
        __syncthreads();
    }
}

// Fused quantize + dw-segment-sum + loss. Block = one dim d (256 blocks x 512 thr).
// kdw parity-split (t&1) to halve LDS-atomic same-address serialization.
__global__ __launch_bounds__(512) void dwq_kernel(
    const float* __restrict__ z, const float* __restrict__ emb,
    const int* __restrict__ idx, const float* __restrict__ ema_emb,
    float* __restrict__ out_q, float* __restrict__ out_ema,
    float* __restrict__ lossp)
{
    __shared__ float kdw[2][KC];
    __shared__ float ecol[KC];
    __shared__ float red[8];
    const int d = blockIdx.x;
    const int t = threadIdx.x;
    #pragma unroll
    for (int k = t; k < KC; k += 512) {
        kdw[0][k] = 0.f; kdw[1][k] = 0.f;
        ecol[k] = emb[(size_t)k * 256 + d];
    }
    __syncthreads();
    float* kd = kdw[t & 1];
    float ls = 0.f;
    #pragma unroll 1
    for (int it = 0; it < 64; ++it) {
        const int e = it * 512 + t;            // float4-unit over (b, hw)
        const int b = e >> 10, hwi = (e & 1023) << 2;
        const size_t zoff = (size_t)b * 1048576 + (size_t)d * 4096 + hwi;
        const float4 zv = *(const float4*)(z + zoff);
        const int4 iv = *(const int4*)(idx + b * 4096 + hwi);
        const float q0 = ecol[iv.x], q1 = ecol[iv.y], q2 = ecol[iv.z], q3 = ecol[iv.w];
        float4 qv; qv.x = q0; qv.y = q1; qv.z = q2; qv.w = q3;
        *(float4*)(out_q + zoff) = qv;
        atomicAdd(&kd[iv.x], zv.x);
        atomicAdd(&kd[iv.y], zv.y);
        atomicAdd(&kd[iv.z], zv.z);
        atomicAdd(&kd[iv.w], zv.w);
        const float d0 = zv.x - q0, d1 = zv.y - q1, d2 = zv.z - q2, d3 = zv.w - q3;
        ls += (d0 * d0 + d1 * d1) + (d2 * d2 + d3 * d3);
    }
    __syncthreads();
    #pragma unroll
    for (int k = t; k < KC; k += 512)
        out_ema[(size_t)k * 256 + d] = 0.99f * ema_emb[(size_t)k * 256 + d]
                                     + 0.01f * (kdw[0][k] + kdw[1][k]);
    #pragma unroll
    for (int off = 32; off > 0; off >>= 1) ls += __shfl_down(ls, off);
    if ((t & 63) == 0) red[t >> 6] = ls;
    __syncthreads();
    if (t == 0) {
        float s = 0.f;
        #pragma unroll
        for (int i = 0; i < 8; ++i) s += red[i];
        lossp[blockIdx.x] = s;
    }
}

__global__ __launch_bounds__(256) void finalize_kernel(
    const float* __restrict__ ema_cs, const float* __restrict__ counts,
    const float* __restrict__ lossp, float* __restrict__ out)
{
    const int i = blockIdx.x * 256 + threadIdx.x;   // 4 blocks
    out[OUT_CS + i] = 0.99f * ema_cs[i] + 0.01f * counts[i];
    if (blockIdx.x == 0) {
        float s = lossp[threadIdx.x];
        #pragma unroll
        for (int off = 32; off > 0; off >>= 1) s += __shfl_down(s, off);
        __shared__ float red[4];
        if ((threadIdx.x & 63) == 0) red[threadIdx.x >> 6] = s;
        __syncthreads();
        if (threadIdx.x == 0)
            out[OUT_LOSS] = 0.25f * ((red[0] + red[1]) + (red[2] + red[3])) / 33554432.0f;
    }
}

// ---------- fallback fp32 GEMM (used if ws too small) ----------
__global__ __launch_bounds__(256) void dist_argmin_kernel(
    const float* __restrict__ z, const float* __restrict__ emb,
    const float* __restrict__ enorm, int* __restrict__ idx_out,
    float* __restrict__ idx_out_f, float* __restrict__ counts)
{
    __shared__ float smem[4096];
    float* As = smem;
    float* Bs = smem + 1024;
    const int tid = threadIdx.x;
    const int tx = tid & 15, ty = tid >> 4;
    const int p0 = blockIdx.x * 128;
    const int b = p0 >> 12, hw0 = p0 & 4095;
    const float* zb = z + (size_t)b * (DD * HWSZ) + hw0;
    const int arow = (tid & 31) * 4, akd = tid >> 5;
    const int bcode = tid >> 1, bj = (tid & 1) * 4;
    float best[8]; int bidx[8];
    #pragma unroll
    for (int i = 0; i < 8; i++) { best[i] = 3.4e38f; bidx[i] = 0; }
    #pragma unroll 1
    for (int cc = 0; cc < 8; ++cc) {
        const int c0 = cc * 128;
        float acc[8][8];
        #pragma unroll
        for (int i = 0; i < 8; i++)
            #pragma unroll
            for (int j = 0; j < 8; j++) acc[i][j] = 0.0f;
        #pragma unroll 1
        for (int dk = 0; dk < 32; ++dk) {
            const int kk0 = dk * 8;
            const float4 av = *(const float4*)(zb + (kk0 + akd) * HWSZ + arow);
            const float4 bv = *(const float4*)(emb + (c0 + bcode) * DD + kk0 + bj);
            __syncthreads();
            *(float4*)(As + akd * 128 + arow) = av;
            Bs[(bj + 0) * 128 + bcode] = bv.x;
            Bs[(bj + 1) * 128 + bcode] = bv.y;
            Bs[(bj + 2) * 128 + bcode] = bv.z;
            Bs[(bj + 3) * 128 + bcode] = bv.w;
            __syncthreads();
            #pragma unroll
            for (int kk = 0; kk < 8; ++kk) {
                const float4 a0 = *(const float4*)(As + kk * 128 + ty * 8);
                const float4 a1 = *(const float4*)(As + kk * 128 + ty * 8 + 4);
                const float4 b0 = *(const float4*)(Bs + kk * 128 + tx * 8);
                const float4 b1 = *(const float4*)(Bs + kk * 128 + tx * 8 + 4);
                const float a[8] = {a0.x,a0.y,a0.z,a0.w,a1.x,a1.y,a1.z,a1.w};
                const float bb[8] = {b0.x,b0.y,b0.z,b0.w,b1.x,b1.y,b1.z,b1.w};
                #pragma unroll
                for (int i = 0; i < 8; i++)
                    #pragma unroll
                    for (int j = 0; j < 8; j++)
                        acc[i][j] = fmaf(a[i], bb[j], acc[i][j]);
            }
        }
        const float4 en0 = *(const float4*)(enorm + c0 + tx * 8);
        const float4 en1 = *(const float4*)(enorm + c0 + tx * 8 + 4);
        const float en[8] = {en0.x,en0.y,en0.z,en0.w,en1.x,en1.y,en1.z,en1.w};
        #pragma unroll
        for (int j = 0; j < 8; j++) {
            const int c = c0 + tx * 8 + j;
            #pragma unroll
            for (int i = 0; i < 8; i++) {
                const float dist = fmaf(-2.0f, acc[i][j], en[j]);
                if (dist < best[i]) { best[i] = dist; bidx[i] = c; }
            }
        }
    }
    __syncthreads();
    float* rmin = smem;
    int* ridx = (int*)(smem + 2048);
    #pragma unroll
    for (int i = 0; i < 8; i++) {
        const int r = ty * 8 + i;
        rmin[r * 16 + tx] = best[i];
        ridx[r * 16 + tx] = bidx[i];
    }
    __syncthreads();
    if (tid < 128) {
        const int r = tid;
        float m = rmin[r * 16]; int mi = ridx[r * 16];
        #pragma unroll
        for (int tt = 1; tt < 16; tt++) {
            const float v = rmin[r * 16 + tt];
            const int vi = ridx[r * 16 + tt];
            if (v < m || (v == m && vi < mi)) { m = v; mi = vi; }
        }
        const int p = p0 + r;
        idx_out[p] = mi;
        idx_out_f[p] = (float)mi;
        atomicAdd(&counts[mi], 1.0f);
    }
}

extern "C" void kernel_launch(void* const* d_in, const int* in_sizes, int n_in,
                              void* d_out, int out_size, void* d_ws, size_t ws_size,
                              hipStream_t stream) {
    const float* z       = (const float*)d_in[0];
    const float* emb     = (const float*)d_in[1];
    const float* ema_cs  = (const float*)d_in[2];
    const float* ema_emb = (const float*)d_in[3];
    float* out = (float*)d_out;
    float* ws  = (float*)d_ws;

    int*   ws_idx    = (int*)(ws + WS_IDX);
    float* ws_counts = ws + WS_COUNTS;
    int*   ws_rcnt   = (int*)(ws + WS_RCNT);
    float* ws_lossp  = ws + WS_LOSSP;
    float* ws_enorm  = ws + WS_ENORM;
    int*   ws_rlist  = (int*)(ws + WS_RLIST);
    unsigned short* ws_eaug = (unsigned short*)(ws + WS_EAUG);
    unsigned short* ws_zaug = (unsigned short*)(ws + WS_ZAUG);

    // zero counts + rescue counter
    hipMemsetAsync(ws_counts, 0, 1025 * sizeof(float), stream);
    hipLaunchKernelGGL(enorm_kernel, dim3(KC), dim3(256), 0, stream, emb, ws_enorm);

    if (ws_size >= (size_t)WS_NEED_FLOATS * sizeof(float)) {
        hipLaunchKernelGGL(convert_z_kernel, dim3(4096), dim3(256), 0, stream, z, ws_zaug);
        hipLaunchKernelGGL(convert_emb_kernel, dim3(64), dim3(256), 0, stream, emb, ws_eaug);
        hipLaunchKernelGGL(gemm_argmin_kernel, dim3(1024), dim3(768), 0, stream,
                           ws_zaug, ws_eaug, ws_enorm, ws_idx, out + OUT_IDX,
                           ws_counts, ws_rcnt, ws_rlist);
        hipLaunchKernelGGL(rescue_kernel, dim3(512), dim3(256), 0, stream,
                           z, emb, ws_enorm, ws_rcnt, ws_rlist,
                           ws_idx, out + OUT_IDX, ws_counts);
    } else {
        hipLaunchKernelGGL(dist_argmin_kernel, dim3(NP / 128), dim3(256), 0, stream,
                           z, emb, ws_enorm, ws_idx, out + OUT_IDX, ws_counts);
    }

    hipLaunchKernelGGL(dwq_kernel, dim3(DD), dim3(512), 0, stream,
                       z, emb, ws_idx, ema_emb, out, out + OUT_EMA, ws_lossp);
    hipLaunchKernelGGL(finalize_kernel, dim3(4), dim3(256), 0, stream,
                       ema_cs, ws_counts, ws_lossp, out);
}

// Round 17
// 776.454 us; speedup vs baseline: 1.3068x; 1.0074x over previous
//
#include <hip/hip_runtime.h>

// Problem constants
#define KC 1024          // num codes
#define DD 256           // embedding dim
#define NP 131072        // B*H*W points
#define HWSZ 4096        // H*W
#define TOTZ 33554432    // B*D*H*W

// d_out float offsets (tuple concat: quantized, loss, indices, cluster_size, ema_emb)
#define OUT_Q    0
#define OUT_LOSS 33554432
#define OUT_IDX  33554433
#define OUT_CS   33685505
#define OUT_EMA  33686529

// workspace float offsets
#define WS_IDX    0         // int[131072]
#define WS_COUNTS 131072    // float[1024]
#define WS_RCNT   132096    // int[1]  (memset together with counts: 1025 floats)
#define WS_LOSSP  132352    // float[256]
#define WS_ENORM  132608    // float[1024]
#define WS_RLIST  133632    // int[131072]
#define WS_EAUG   264704    // ushort[786432] = 393216 floats (8 cc x 12 ks x 16KB)
#define WS_ZAUG   657920    // ushort[67108864] = 33554432 floats (1024 pt x 8 ksA x 16KB)
#define WS_NEED_FLOATS (WS_ZAUG + 33554432)

#define MARGIN 0.0625f
#define RTILE 16

typedef __attribute__((ext_vector_type(8))) short bf16x8;
typedef __attribute__((ext_vector_type(4))) float f32x4;

__device__ inline unsigned short f2bf_rne(float x) {
    unsigned u = __float_as_uint(x);
    unsigned r = u + 0x7FFFu + ((u >> 16) & 1u);
    return (unsigned short)(r >> 16);
}
__device__ inline float bf2f(unsigned short h) {
    return __uint_as_float(((unsigned)h) << 16);
}
__device__ inline void gl_lds16(const void* g, void* l) {
    __builtin_amdgcn_global_load_lds(
        (const __attribute__((address_space(1))) unsigned int*)g,
        (__attribute__((address_space(3))) unsigned int*)l, 16, 0, 0);
}
// monotone float->uint, packed with code index: min key = min dist, tie -> min idx
__device__ inline unsigned long long packkey(float d, int c) {
    unsigned u = __float_as_uint(d);
    u = (u & 0x80000000u) ? ~u : (u | 0x80000000u);
    return (((unsigned long long)u) << 32) | (unsigned)c;
}

__global__ __launch_bounds__(256) void enorm_kernel(const float* __restrict__ emb,
                                                    float* __restrict__ enorm) {
    const int k = blockIdx.x;
    float v = emb[k * DD + threadIdx.x];
    v *= v;
    #pragma unroll
    for (int off = 32; off > 0; off >>= 1) v += __shfl_down(v, off);
    __shared__ float red[4];
    if ((threadIdx.x & 63) == 0) red[threadIdx.x >> 6] = v;
    __syncthreads();
    if (threadIdx.x == 0) enorm[k] = (red[0] + red[1]) + (red[2] + red[3]);
}

// z_aug: [pt(1024)][ksA(8)][kc(2)][mt(8)][lane(64)][8 bf16]
// ksA 0..3 = hi, 4..7 = mid. One block computes hi AND mid (z read once).
__global__ __launch_bounds__(256) void convert_z_kernel(
    const float* __restrict__ z, unsigned short* __restrict__ zaug)
{
    const int blk = blockIdx.x;            // pt*4 + kslot
    const int pt = blk >> 2, kslot = blk & 3;
    const int kbase0 = kslot * 64;
    unsigned short* outH = zaug + (size_t)(pt * 8 + kslot) * 8192;
    unsigned short* outM = zaug + (size_t)(pt * 8 + 4 + kslot) * 8192;
    #pragma unroll
    for (int i = 0; i < 4; ++i) {
        const int f = i * 256 + threadIdx.x;   // fragment index [0,1024)
        const int kc = f >> 9, mt = (f >> 6) & 7, lane = f & 63;
        const int q = lane >> 4, col = lane & 15;
        const int p = pt * 128 + mt * 16 + col;
        const int b = p >> 12, hw = p & 4095;
        const int k0 = kbase0 + kc * 32 + q * 8;
        const float* src = z + (size_t)b * 1048576 + (size_t)k0 * 4096 + hw;
        unsigned short vh[8], vm[8];
        #pragma unroll
        for (int j = 0; j < 8; ++j) {
            const float x = src[j * 4096];
            const unsigned short h = f2bf_rne(x);
            vh[j] = h;
            vm[j] = f2bf_rne(x - bf2f(h));
        }
        *(uint4*)(outH + (size_t)f * 8) = *(uint4*)vh;
        *(uint4*)(outM + (size_t)f * 8) = *(uint4*)vm;
    }
}

// emb_aug: [cc(8)][ks(12)][kc(2)][nt(8)][lane(64)][8 bf16]; ks 0..3 hi, 8..11 mid.
// ks 4..7 are not read -> only 8 ks generated.
__global__ __launch_bounds__(256) void convert_emb_kernel(
    const float* __restrict__ emb, unsigned short* __restrict__ eaug)
{
    const int blk = blockIdx.x;            // cc*8 + ks'
    const int cc = blk >> 3, ksp = blk & 7;
    const int ks = ksp + ((ksp >= 4) ? 4 : 0);   // {0,1,2,3,8,9,10,11}
    const int mode = (ks >= 8);
    unsigned short* outp = eaug + (size_t)(cc * 12 + ks) * 8192;
    #pragma unroll
    for (int i = 0; i < 4; ++i) {
        const int f = i * 256 + threadIdx.x;
        const int kc = f >> 9, nt = (f >> 6) & 7, lane = f & 63;
        const int q = lane >> 4, col = lane & 15;
        const int n = cc * 128 + nt * 16 + col;
        const int k0 = ((ks * 64) & 255) + kc * 32 + q * 8;
        const float* src = emb + (size_t)n * 256 + k0;
        unsigned short v[8];
        #pragma unroll
        for (int j = 0; j < 8; ++j) {
            const float x = src[j];
            const unsigned short h = f2bf_rne(x);
            v[j] = mode ? f2bf_rne(x - bf2f(h)) : h;
        }
        *(uint4*)(outp + (size_t)f * 8) = *(uint4*)v;
    }
}

// MFMA GEMM + fused argmin. R13 = R12 (768 thr, 12 waves, 3/SIMD, 170-reg cap,
// clean at 132 regs) + LOAD PIPELINING. R1/R3/R12 all pinned at 28-31%
// MfmaUtil with nothing saturated (HBM 3%, L2 ~20%, VALU 27%) -> latency-bound:
// each s-step was a serial chain (B vm-wait ~200cy -> af lgkm-wait ~120cy ->
// MFMA ~80cy). Fix: (a) issue BOTH kci's B-loads (8 loads) before any MFMA of
// the step -- kci0's MFMAs cover kci1's vm-wait; (b) unroll s4-loops x2 so the
// next step's loads/ds_reads interleave with current MFMAs (compiler emits
// partial waitcnt). Worst-case live: acc 64 + B 64 + af 8 + addr ~25 = 161 <= 170.
// MFMA accumulation order per acc unchanged -> absmax 0.03125.
__global__ __launch_bounds__(768, 3) void gemm_argmin_kernel(
    const unsigned short* __restrict__ zaug, const unsigned short* __restrict__ eaug,
    const float* __restrict__ enorm, int* __restrict__ idx_out,
    float* __restrict__ idx_out_f, float* __restrict__ counts,
    int* __restrict__ rcnt, int* __restrict__ rlist)
{
    __shared__ float smem[38912];                 // 128 KB A slabs + 24 KB dump
    unsigned short* aS = (unsigned short*)smem;   // [slab8][kc2][mt8][lane64][8]
    float* dB = smem + 32768;                     // [16cg][128pt]
    float* dS = smem + 34816;
    int*   dI = (int*)(smem + 36864);
    const int t = threadIdx.x, w = t >> 6, lane = t & 63;
    const int q = lane >> 4, col = lane & 15;
    const int pt = blockIdx.x;                    // 1024 tiles of 128 points

    const unsigned short* zb = zaug + (size_t)pt * 65536;   // halfword units

    // issue hi slabs (chunks 0..4095, 16B each)
    #pragma unroll 1
    for (int c = t; c < 4096; c += 768)
        gl_lds16(zb + c * 8, aS + c * 8);
    __syncthreads();                              // hi resident (vmcnt drained)
    // issue mid slabs (chunks 4096..8191) -- land under tile #1 phase A
    #pragma unroll 1
    for (int c = 4096 + t; c < 8192; c += 768)
        gl_lds16(zb + c * 8, aS + c * 8);

// af in pairs (8 arch regs); mi order 0,1,2,3 preserved.
#define COMPUTE_SET(BREG, SLAB)                                               \
    {                                                                         \
        _Pragma("unroll")                                                     \
        for (int mp = 0; mp < 2; ++mp) {                                      \
            bf16x8 af0 = *(const bf16x8*)(aS + (SLAB) * 8192 + kci * 4096     \
                                          + (g4 + mp * 2) * 512 + lane * 8);  \
            bf16x8 af1 = *(const bf16x8*)(aS + (SLAB) * 8192 + kci * 4096     \
                                          + (g4 + mp * 2 + 1) * 512           \
                                          + lane * 8);                        \
            __builtin_amdgcn_s_setprio(1);                                    \
            _Pragma("unroll")                                                 \
            for (int ni = 0; ni < 4; ++ni)                                    \
                acc[mp * 2][ni] = __builtin_amdgcn_mfma_f32_16x16x32_bf16(    \
                    af0, BREG[ni], acc[mp * 2][ni], 0, 0, 0);                 \
            _Pragma("unroll")                                                 \
            for (int ni = 0; ni < 4; ++ni)                                    \
                acc[mp * 2 + 1][ni] = __builtin_amdgcn_mfma_f32_16x16x32_bf16(\
                    af1, BREG[ni], acc[mp * 2 + 1][ni], 0, 0, 0);             \
            __builtin_amdgcn_s_setprio(0);                                    \
        }                                                                     \
    }

// phase A: B mid (ks 8..11) x A hi slabs. Both kci loads issued up front.
#define PHASE_A                                                               \
    _Pragma("unroll 2")                                                       \
    for (int s4 = 0; s4 < 4; ++s4) {                                          \
        const int ksE = 8 + s4, slabH = s4;                                   \
        bf16x8 bfA[4], bfB[4];                                                \
        _Pragma("unroll")                                                     \
        for (int ni = 0; ni < 4; ++ni)                                        \
            bfA[ni] = *(const bf16x8*)(eb + ksE * 8192 + ni * 512);           \
        _Pragma("unroll")                                                     \
        for (int ni = 0; ni < 4; ++ni)                                        \
            bfB[ni] = *(const bf16x8*)(eb + ksE * 8192 + 4096 + ni * 512);    \
        { const int kci = 0; COMPUTE_SET(bfA, slabH) }                        \
        { const int kci = 1; COMPUTE_SET(bfB, slabH) }                        \
    }

// phase B: B hi (ks 0..3) x (A hi + A mid). Both kci loads issued up front.
#define PHASE_B                                                               \
    _Pragma("unroll 2")                                                       \
    for (int s4 = 0; s4 < 4; ++s4) {                                          \
        const int ksE = s4, slabH = s4;                                       \
        bf16x8 bfA[4], bfB[4];                                                \
        _Pragma("unroll")                                                     \
        for (int ni = 0; ni < 4; ++ni)                                        \
            bfA[ni] = *(const bf16x8*)(eb + ksE * 8192 + ni * 512);           \
        _Pragma("unroll")                                                     \
        for (int ni = 0; ni < 4; ++ni)                                        \
            bfB[ni] = *(const bf16x8*)(eb + ksE * 8192 + 4096 + ni * 512);    \
        { const int kci = 0; COMPUTE_SET(bfA, slabH) COMPUTE_SET(bfA, 4 + slabH) } \
        { const int kci = 1; COMPUTE_SET(bfB, slabH) COMPUTE_SET(bfB, 4 + slabH) } \
    }

// epilogue: dist = en - 2*dot; ni-merge; 4-step col shfl-reduce 16->1;
// col==0 lanes write (best,2nd,idx) per point into dump[cg][ptl].
#define EPILOGUE                                                              \
    {                                                                         \
        const int cbase = cg * 64;                                            \
        _Pragma("unroll")                                                     \
        for (int mi = 0; mi < 4; ++mi) {                                      \
            _Pragma("unroll")                                                 \
            for (int r = 0; r < 4; ++r) {                                     \
                const float en0 = enorm[cbase + col];                         \
                const float en1 = enorm[cbase + 16 + col];                    \
                const float en2 = enorm[cbase + 32 + col];                    \
                const float en3 = enorm[cbase + 48 + col];                    \
                float v0 = fmaf(-2.f, acc[mi][0][r], en0);                    \
                float v1 = fmaf(-2.f, acc[mi][1][r], en1);                    \
                float v2 = fmaf(-2.f, acc[mi][2][r], en2);                    \
                float v3 = fmaf(-2.f, acc[mi][3][r], en3);                    \
                const int nb = cbase + col;                                   \
                float b01 = fminf(v0, v1), x01 = fmaxf(v0, v1);               \
                int   i01 = (v1 < v0) ? nb + 16 : nb;                         \
                float b23 = fminf(v2, v3), x23 = fmaxf(v2, v3);               \
                int   i23 = (v3 < v2) ? nb + 48 : nb + 32;                    \
                float b = fminf(b01, b23);                                    \
                int   ib = (b23 < b01) ? i23 : i01;                           \
                float s2 = fminf(fmaxf(b01, b23), fminf(x01, x23));           \
                _Pragma("unroll")                                             \
                for (int m = 1; m < 16; m <<= 1) {                            \
                    const float ob = __shfl_xor(b, m);                        \
                    const float os = __shfl_xor(s2, m);                       \
                    const int   oi = __shfl_xor(ib, m);                       \
                    const bool sw = ob < b;                                   \
                    const float cand = sw ? b : ob;                           \
                    const float osel = sw ? os : s2;                          \
                    b  = sw ? ob : b;                                         \
                    ib = sw ? oi : ib;                                        \
                    s2 = fminf(cand, osel);                                   \
                }                                                             \
                if (col == 0) {                                               \
                    const int ptl = pth * 64 + mi * 16 + q * 4 + r;           \
                    dB[cg * 128 + ptl] = b;                                   \
                    dS[cg * 128 + ptl] = s2;                                  \
                    dI[cg * 128 + ptl] = ib;                                  \
                }                                                             \
            }                                                                 \
        }                                                                     \
    }

#define INIT_ACC                                                              \
    _Pragma("unroll")                                                         \
    for (int mi = 0; mi < 4; ++mi)                                            \
        _Pragma("unroll")                                                     \
        for (int ni = 0; ni < 4; ++ni) acc[mi][ni] = (f32x4){0.f,0.f,0.f,0.f};

#define TILE_SETUP(TAU)                                                       \
    const int pth = (TAU) & 1, cg = (TAU) >> 1;                               \
    const int g4 = pth * 4;                                                   \
    const unsigned short* eb = eaug + (size_t)(cg >> 1) * 98304               \
                             + (cg & 1) * 2048 + (size_t)lane * 8;

    f32x4 acc[4][4];
    {   // tile #1 (tau = w): phase A under mid staging, barrier, phase B
        TILE_SETUP(w)
        INIT_ACC
        PHASE_A
        __syncthreads();                          // mid slabs resident
        PHASE_B
        EPILOGUE
    }
    #pragma unroll 1
    for (int ti = 1; ti < 3; ++ti) {
        const int tau = w + ti * 12;
        if (tau < 32) {
            TILE_SETUP(tau)
            INIT_ACC
            PHASE_A
            PHASE_B
            EPILOGUE
        }
    }
#undef TILE_SETUP
#undef INIT_ACC
#undef EPILOGUE
#undef PHASE_B
#undef PHASE_A
#undef COMPUTE_SET

    __syncthreads();                              // all dumps visible
    if (t < 128) {
        float B = 3.4e38f, S = 3.4e38f; int I = 0;
        #pragma unroll
        for (int cg = 0; cg < 16; ++cg) {
            const float b = dB[cg * 128 + t];
            const float s2 = dS[cg * 128 + t];
            const int   i = dI[cg * 128 + t];
            if (b < B) { S = fminf(B, s2); B = b; I = i; }
            else       { S = fminf(S, b); }
        }
        const int p = pt * 128 + t;
        idx_out[p] = I;
        idx_out_f[p] = (float)I;
        atomicAdd(&counts[I], 1.0f);
        if (S - B < MARGIN) {
            const int pos = atomicAdd(rcnt, 1);
            rlist[pos] = p;
        }
    }
}

// Batched exact fp32 re-argmin: 16 points staged in LDS, each thread owns 4
// codes (c = ci*256 + t) with dot[16][4] register accumulators -> per d4 only
// 16 LDS reads + 4 e-loads for 256 FMA. Numerics identical to prior version.
__global__ __launch_bounds__(256) void rescue_kernel(
    const float* __restrict__ z, const float* __restrict__ emb,
    const float* __restrict__ enorm, const int* __restrict__ rcnt,
    const int* __restrict__ rlist, int* __restrict__ idx_out,
    float* __restrict__ idx_out_f, float* __restrict__ counts)
{
    __shared__ float zl[RTILE][DD];
    __shared__ unsigned long long lkey[RTILE];
    const int n = *rcnt;
    if (n <= 0) return;
    const int ntiles = (n + RTILE - 1) / RTILE;
    const int t = threadIdx.x;
    const int slot = t & 15, drow = t >> 4;    // thread loads 16 dims for one slot
    #pragma unroll 1
    for (int tile = blockIdx.x; tile < ntiles; tile += gridDim.x) {
        const int base = tile * RTILE;
        {
            const int ridx = min(base + slot, n - 1);   // clamp: dup compute, guarded update
            const int p = rlist[ridx];
            const int b = p >> 12, hw = p & 4095;
            const float* zp = z + (size_t)b * 1048576 + hw;
            #pragma unroll
            for (int j = 0; j < 16; ++j)
                zl[slot][drow * 16 + j] = zp[(size_t)(drow * 16 + j) * 4096];
        }
        if (t < RTILE) lkey[t] = ~0ull;
        __syncthreads();
        float dot[RTILE][4];
        #pragma unroll
        for (int p = 0; p < RTILE; ++p)
            #pragma unroll
            for (int ci = 0; ci < 4; ++ci) dot[p][ci] = 0.f;
        #pragma unroll 1
        for (int d4 = 0; d4 < 64; ++d4) {
            float4 ev[4];
            #pragma unroll
            for (int ci = 0; ci < 4; ++ci)
                ev[ci] = *(const float4*)(emb + (size_t)(ci * 256 + t) * 256 + d4 * 4);
            #pragma unroll
            for (int p = 0; p < RTILE; ++p) {
                const float4 zv = *(const float4*)(&zl[p][d4 * 4]);
                #pragma unroll
                for (int ci = 0; ci < 4; ++ci) {
                    dot[p][ci] = fmaf(zv.x, ev[ci].x, dot[p][ci]);
                    dot[p][ci] = fmaf(zv.y, ev[ci].y, dot[p][ci]);
                    dot[p][ci] = fmaf(zv.z, ev[ci].z, dot[p][ci]);
                    dot[p][ci] = fmaf(zv.w, ev[ci].w, dot[p][ci]);
                }
            }
        }
        float en[4];
        #pragma unroll
        for (int ci = 0; ci < 4; ++ci) en[ci] = enorm[ci * 256 + t];
        #pragma unroll
        for (int p = 0; p < RTILE; ++p) {
            unsigned long long k = packkey(fmaf(-2.f, dot[p][0], en[0]), t);
            #pragma unroll
            for (int ci = 1; ci < 4; ++ci) {
                const unsigned long long k2 =
                    packkey(fmaf(-2.f, dot[p][ci], en[ci]), ci * 256 + t);
                k = (k2 < k) ? k2 : k;
            }
            atomicMin(&lkey[p], k);
        }
        __syncthreads();
        if (t < RTILE && base + t < n) {
            const int p = rlist[base + t];
            const int fc = (int)(lkey[t] & 0xFFFFFFFFull);
            const int old = idx_out[p];
            if (fc != old) {
                atomicAdd(&counts[old], -1.0f);
                atomicAdd(&counts[fc], 1.0f);
                idx_out[p] = fc;
                idx_out_f[p] = (float)fc;
            }
        }
        __syncthreads();
    }
}

// Fused quantize + dw-segment-sum + loss. Block = one dim d (256 blocks x 512 thr).
// kdw parity-split (t&1) to halve LDS-atomic same-address serialization.
__global__ __launch_bounds__(512) void dwq_kernel(
    const float* __restrict__ z, const float* __restrict__ emb,
    const int* __restrict__ idx, const float* __restrict__ ema_emb,
    float* __restrict__ out_q, float* __restrict__ out_ema,
    float* __restrict__ lossp)
{
    __shared__ float kdw[2][KC];
    __shared__ float ecol[KC];
    __shared__ float red[8];
    const int d = blockIdx.x;
    const int t = threadIdx.x;
    #pragma unroll
    for (int k = t; k < KC; k += 512) {
        kdw[0][k] = 0.f; kdw[1][k] = 0.f;
        ecol[k] = emb[(size_t)k * 256 + d];
    }
    __syncthreads();
    float* kd = kdw[t & 1];
    float ls = 0.f;
    #pragma unroll 1
    for (int it = 0; it < 64; ++it) {
        const int e = it * 512 + t;            // float4-unit over (b, hw)
        const int b = e >> 10, hwi = (e & 1023) << 2;
        const size_t zoff = (size_t)b * 1048576 + (size_t)d * 4096 + hwi;
        const float4 zv = *(const float4*)(z + zoff);
        const int4 iv = *(const int4*)(idx + b * 4096 + hwi);
        const float q0 = ecol[iv.x], q1 = ecol[iv.y], q2 = ecol[iv.z], q3 = ecol[iv.w];
        float4 qv; qv.x = q0; qv.y = q1; qv.z = q2; qv.w = q3;
        *(float4*)(out_q + zoff) = qv;
        atomicAdd(&kd[iv.x], zv.x);
        atomicAdd(&kd[iv.y], zv.y);
        atomicAdd(&kd[iv.z], zv.z);
        atomicAdd(&kd[iv.w], zv.w);
        const float d0 = zv.x - q0, d1 = zv.y - q1, d2 = zv.z - q2, d3 = zv.w - q3;
        ls += (d0 * d0 + d1 * d1) + (d2 * d2 + d3 * d3);
    }
    __syncthreads();
    #pragma unroll
    for (int k = t; k < KC; k += 512)
        out_ema[(size_t)k * 256 + d] = 0.99f * ema_emb[(size_t)k * 256 + d]
                                     + 0.01f * (kdw[0][k] + kdw[1][k]);
    #pragma unroll
    for (int off = 32; off > 0; off >>= 1) ls += __shfl_down(ls, off);
    if ((t & 63) == 0) red[t >> 6] = ls;
    __syncthreads();
    if (t == 0) {
        float s = 0.f;
        #pragma unroll
        for (int i = 0; i < 8; ++i) s += red[i];
        lossp[blockIdx.x] = s;
    }
}

__global__ __launch_bounds__(256) void finalize_kernel(
    const float* __restrict__ ema_cs, const float* __restrict__ counts,
    const float* __restrict__ lossp, float* __restrict__ out)
{
    const int i = blockIdx.x * 256 + threadIdx.x;   // 4 blocks
    out[OUT_CS + i] = 0.99f * ema_cs[i] + 0.01f * counts[i];
    if (blockIdx.x == 0) {
        float s = lossp[threadIdx.x];
        #pragma unroll
        for (int off = 32; off > 0; off >>= 1) s += __shfl_down(s, off);
        __shared__ float red[4];
        if ((threadIdx.x & 63) == 0) red[threadIdx.x >> 6] = s;
        __syncthreads();
        if (threadIdx.x == 0)
            out[OUT_LOSS] = 0.25f * ((red[0] + red[1]) + (red[2] + red[3])) / 33554432.0f;
    }
}

// ---------- fallback fp32 GEMM (used if ws too small) ----------
__global__ __launch_bounds__(256) void dist_argmin_kernel(
    const float* __restrict__ z, const float* __restrict__ emb,
    const float* __restrict__ enorm, int* __restrict__ idx_out,
    float* __restrict__ idx_out_f, float* __restrict__ counts)
{
    __shared__ float smem[4096];
    float* As = smem;
    float* Bs = smem + 1024;
    const int tid = threadIdx.x;
    const int tx = tid & 15, ty = tid >> 4;
    const int p0 = blockIdx.x * 128;
    const int b = p0 >> 12, hw0 = p0 & 4095;
    const float* zb = z + (size_t)b * (DD * HWSZ) + hw0;
    const int arow = (tid & 31) * 4, akd = tid >> 5;
    const int bcode = tid >> 1, bj = (tid & 1) * 4;
    float best[8]; int bidx[8];
    #pragma unroll
    for (int i = 0; i < 8; i++) { best[i] = 3.4e38f; bidx[i] = 0; }
    #pragma unroll 1
    for (int cc = 0; cc < 8; ++cc) {
        const int c0 = cc * 128;
        float acc[8][8];
        #pragma unroll
        for (int i = 0; i < 8; i++)
            #pragma unroll
            for (int j = 0; j < 8; j++) acc[i][j] = 0.0f;
        #pragma unroll 1
        for (int dk = 0; dk < 32; ++dk) {
            const int kk0 = dk * 8;
            const float4 av = *(const float4*)(zb + (kk0 + akd) * HWSZ + arow);
            const float4 bv = *(const float4*)(emb + (c0 + bcode) * DD + kk0 + bj);
            __syncthreads();
            *(float4*)(As + akd * 128 + arow) = av;
            Bs[(bj + 0) * 128 + bcode] = bv.x;
            Bs[(bj + 1) * 128 + bcode] = bv.y;
            Bs[(bj + 2) * 128 + bcode] = bv.z;
            Bs[(bj + 3) * 128 + bcode] = bv.w;
            __syncthreads();
            #pragma unroll
            for (int kk = 0; kk < 8; ++kk) {
                const float4 a0 = *(const float4*)(As + kk * 128 + ty * 8);
                const float4 a1 = *(const float4*)(As + kk * 128 + ty * 8 + 4);
                const float4 b0 = *(const float4*)(Bs + kk * 128 + tx * 8);
                const float4 b1 = *(const float4*)(Bs + kk * 128 + tx * 8 + 4);
                const float a[8] = {a0.x,a0.y,a0.z,a0.w,a1.x,a1.y,a1.z,a1.w};
                const float bb[8] = {b0.x,b0.y,b0.z,b0.w,b1.x,b1.y,b1.z,b1.w};
                #pragma unroll
                for (int i = 0; i < 8; i++)
                    #pragma unroll
                    for (int j = 0; j < 8; j++)
                        acc[i][j] = fmaf(a[i], bb[j], acc[i][j]);
            }
        }
        const float4 en0 = *(const float4*)(enorm + c0 + tx * 8);
        const float4 en1 = *(const float4*)(enorm + c0 + tx * 8 + 4);
        const float en[8] = {en0.x,en0.y,en0.z,en0.w,en1.x,en1.y,en1.z,en1.w};
        #pragma unroll
        for (int j = 0; j < 8; j++) {
            const int c = c0 + tx * 8 + j;
            #pragma unroll
            for (int i = 0; i < 8; i++) {
                const float dist = fmaf(-2.0f, acc[i][j], en[j]);
                if (dist < best[i]) { best[i] = dist; bidx[i] = c; }
            }
        }
    }
    __syncthreads();
    float* rmin = smem;
    int* ridx = (int*)(smem + 2048);
    #pragma unroll
    for (int i = 0; i < 8; i++) {
        const int r = ty * 8 + i;
        rmin[r * 16 + tx] = best[i];
        ridx[r * 16 + tx] = bidx[i];
    }
    __syncthreads();
    if (tid < 128) {
        const int r = tid;
        float m = rmin[r * 16]; int mi = ridx[r * 16];
        #pragma unroll
        for (int tt = 1; tt < 16; tt++) {
            const float v = rmin[r * 16 + tt];
            const int vi = ridx[r * 16 + tt];
            if (v < m || (v == m && vi < mi)) { m = v; mi = vi; }
        }
        const int p = p0 + r;
        idx_out[p] = mi;
        idx_out_f[p] = (float)mi;
        atomicAdd(&counts[mi], 1.0f);
    }
}

extern "C" void kernel_launch(void* const* d_in, const int* in_sizes, int n_in,
                              void* d_out, int out_size, void* d_ws, size_t ws_size,
                              hipStream_t stream) {
    const float* z       = (const float*)d_in[0];
    const float* emb     = (const float*)d_in[1];
    const float* ema_cs  = (const float*)d_in[2];
    const float* ema_emb = (const float*)d_in[3];
    float* out = (float*)d_out;
    float* ws  = (float*)d_ws;

    int*   ws_idx    = (int*)(ws + WS_IDX);
    float* ws_counts = ws + WS_COUNTS;
    int*   ws_rcnt   = (int*)(ws + WS_RCNT);
    float* ws_lossp  = ws + WS_LOSSP;
    float* ws_enorm  = ws + WS_ENORM;
    int*   ws_rlist  = (int*)(ws + WS_RLIST);
    unsigned short* ws_eaug = (unsigned short*)(ws + WS_EAUG);
    unsigned short* ws_zaug = (unsigned short*)(ws + WS_ZAUG);

    // zero counts + rescue counter
    hipMemsetAsync(ws_counts, 0, 1025 * sizeof(float), stream);
    hipLaunchKernelGGL(enorm_kernel, dim3(KC), dim3(256), 0, stream, emb, ws_enorm);

    if (ws_size >= (size_t)WS_NEED_FLOATS * sizeof(float)) {
        hipLaunchKernelGGL(convert_z_kernel, dim3(4096), dim3(256), 0, stream, z, ws_zaug);
        hipLaunchKernelGGL(convert_emb_kernel, dim3(64), dim3(256), 0, stream, emb, ws_eaug);
        hipLaunchKernelGGL(gemm_argmin_kernel, dim3(1024), dim3(768), 0, stream,
                           ws_zaug, ws_eaug, ws_enorm, ws_idx, out + OUT_IDX,
                           ws_counts, ws_rcnt, ws_rlist);
        hipLaunchKernelGGL(rescue_kernel, dim3(512), dim3(256), 0, stream,
                           z, emb, ws_enorm, ws_rcnt, ws_rlist,
                           ws_idx, out + OUT_IDX, ws_counts);
    } else {
        hipLaunchKernelGGL(dist_argmin_kernel, dim3(NP / 128), dim3(256), 0, stream,
                           z, emb, ws_enorm, ws_idx, out + OUT_IDX, ws_counts);
    }

    hipLaunchKernelGGL(dwq_kernel, dim3(DD), dim3(512), 0, stream,
                       z, emb, ws_idx, ema_emb, out, out + OUT_EMA, ws_lossp);
    hipLaunchKernelGGL(finalize_kernel, dim3(4), dim3(256), 0, stream,
                       ema_cs, ws_counts, ws_lossp, out);
}